// Round 7
// baseline (278.617 us; speedup 1.0000x reference)
//
#include <hip/hip_runtime.h>

#define NELEM (4096 * 4096)
#define KDIM 4096
#define NDIM 4096
#define DOUT 4096
#define EPSQ 1e-8f
#define STRIDE_MEM (2048 * 256)   // streaming kernels: exact grid, compile-time trip counts

typedef __attribute__((ext_vector_type(4))) int i32x4;
typedef __attribute__((ext_vector_type(16))) int i32x16;

typedef __attribute__((address_space(3))) void lds_void;
typedef const __attribute__((address_space(1))) void gbl_void;

__device__ __forceinline__ void load_lds16(const void* g, void* l) {
    __builtin_amdgcn_global_load_lds((gbl_void*)g, (lds_void*)l, 16, 0, 0);
}

__device__ __forceinline__ float wave_max64(float v) {
#pragma unroll
    for (int off = 32; off > 0; off >>= 1)
        v = fmaxf(v, __shfl_down(v, off));
    return v;
}

// ws u32 layout: [16j] x-slots, [16j+4] w-slots (j=0..7), [128] b, [132] out-amax,
//                [136] done-counter, [140] flag (1 = gemm finalized out, 2 = poison)

// ---------------- kernel 1: fused absmax of x, w, b (8-slot spread atomics) ----------------
__global__ __launch_bounds__(256) void absmax_xwb(
    const float4* __restrict__ x, const float4* __restrict__ w,
    const float* __restrict__ b, unsigned* __restrict__ amax)
{
    float mx = 0.f, mw = 0.f;
    int i = blockIdx.x * 256 + threadIdx.x;
#pragma unroll
    for (int it = 0; it < 8; ++it, i += STRIDE_MEM) {   // 8 * 524288 = NELEM/4 exactly
        float4 a = x[i];
        float4 c = w[i];
        mx = fmaxf(mx, fmaxf(fmaxf(fabsf(a.x), fabsf(a.y)), fmaxf(fabsf(a.z), fabsf(a.w))));
        mw = fmaxf(mw, fmaxf(fmaxf(fabsf(c.x), fabsf(c.y)), fmaxf(fabsf(c.z), fabsf(c.w))));
    }
    float mb = 0.f;
    if (blockIdx.x == 0) {
#pragma unroll
        for (int t = 0; t < DOUT / 256; ++t)
            mb = fmaxf(mb, fabsf(b[t * 256 + threadIdx.x]));
    }

    mx = wave_max64(mx); mw = wave_max64(mw); mb = wave_max64(mb);
    __shared__ float red[3][4];
    const int wave = threadIdx.x >> 6, lane = threadIdx.x & 63;
    if (lane == 0) { red[0][wave] = mx; red[1][wave] = mw; red[2][wave] = mb; }
    __syncthreads();
    if (threadIdx.x == 0) {
        float r0 = fmaxf(fmaxf(red[0][0], red[0][1]), fmaxf(red[0][2], red[0][3]));
        float r1 = fmaxf(fmaxf(red[1][0], red[1][1]), fmaxf(red[1][2], red[1][3]));
        const int sl = (blockIdx.x & 7) * 16;           // 8 line-padded slots
        atomicMax(&amax[sl], __float_as_uint(r0));
        atomicMax(&amax[sl + 4], __float_as_uint(r1));
        if (blockIdx.x == 0) {
            float r2 = fmaxf(fmaxf(red[2][0], red[2][1]), fmaxf(red[2][2], red[2][3]));
            atomicMax(&amax[128], __float_as_uint(r2));
        }
    }
}

// reduce the 8 spread slots (wave-uniform loads, hits L2)
__device__ __forceinline__ void load_scales(const unsigned* __restrict__ amax,
                                            float& sx, float& sw) {
    float sxm = 0.f, swm = 0.f;
#pragma unroll
    for (int j = 0; j < 8; ++j) {
        sxm = fmaxf(sxm, __uint_as_float(amax[j * 16]));
        swm = fmaxf(swm, __uint_as_float(amax[j * 16 + 4]));
    }
    sx = fmaxf(sxm / 127.0f, EPSQ);
    sw = fmaxf(swm / 7.0f, EPSQ);
}

// quantize 4 floats to int8 levels, pack into one int32
__device__ __forceinline__ int pack4(float4 a, float s, float qmax) {
    int b0 = (int)fminf(fmaxf(rintf(a.x / s), -qmax), qmax);  // rintf = round-half-even = jnp.round
    int b1 = (int)fminf(fmaxf(rintf(a.y / s), -qmax), qmax);
    int b2 = (int)fminf(fmaxf(rintf(a.z / s), -qmax), qmax);
    int b3 = (int)fminf(fmaxf(rintf(a.w / s), -qmax), qmax);
    return (b0 & 0xff) | ((b1 & 0xff) << 8) | ((b2 & 0xff) << 16) | (b3 << 24);
}

// ---------------- kernel 2: fused quantize (unit-stride) ----------------
__global__ __launch_bounds__(256) void quant_xwb(
    const float4* __restrict__ x, const float4* __restrict__ w,
    const float* __restrict__ b, const unsigned* __restrict__ amax,
    int* __restrict__ qx, int* __restrict__ qw, float* __restrict__ bq)
{
    float sx, sw;
    load_scales(amax, sx, sw);
    int i = blockIdx.x * 256 + threadIdx.x;
#pragma unroll
    for (int it = 0; it < 8; ++it, i += STRIDE_MEM) {
        qx[i] = pack4(x[i], sx, 127.f);
        qw[i] = pack4(w[i], sw, 7.f);
    }
    if (blockIdx.x == 0) {
        const float sb = fmaxf(__uint_as_float(amax[128]) / 127.0f, EPSQ);
#pragma unroll
        for (int t = 0; t < DOUT / 256; ++t) {
            int j = t * 256 + threadIdx.x;
            float q = fminf(fmaxf(rintf(b[j] / sb), -127.f), 127.f);
            bq[j] = q * sb;
        }
    }
}

// ---------------- kernel 3: 256x256 i8 GEMM, 32x32x32 MFMA, pipelined + spin-fused quant ----
// K-loop identical to R6 except the swizzle involution gains row-bit-4:
//   f(row) = ((row>>1)&3) ^ ((row>>4)&1)
// -> quarter-wave slot constants 0,1,1,0 (R4's zero-conflict class) instead of 0,0,1,1.
// Epilogue: absmax -> done-counter -> bounded spin (256 blocks, 1/CU, all co-resident by LDS)
// -> read final scale -> single quantized store. Timeout poisons flag; final_quant guard fixes.
__global__ __launch_bounds__(512, 2) void gemm_i8_8p(
    const char* __restrict__ qx,   // int8 [4096][4096] (M,K) row-major
    const char* __restrict__ qw,   // int8 [4096][4096] (N,K) row-major
    const float* __restrict__ bq,
    const unsigned* __restrict__ amax,
    float* __restrict__ out,
    unsigned* __restrict__ ws)     // full ws-u32 base: [132] amax_out, [136] done, [140] flag
{
    constexpr int K = KDIM, N = NDIM;
    __shared__ char lds[131072];          // A ring: [4][2half][128][64] @0; B ring @65536
    char* ldsA = lds;
    char* ldsB = lds + 65536;

    const int tid = threadIdx.x;
    const int wave = tid >> 6, lane = tid & 63;
    // T1 XCD swizzle: 256 blocks, 8 XCDs, chunk 32
    const int swz = (blockIdx.x & 7) * 32 + (blockIdx.x >> 3);
    const int bm = swz >> 4, bn = swz & 15;
    const int wm2 = wave >> 2;            // M-half (0..1), 128 rows
    const int wn4 = wave & 3;             // N-quarter (0..3), 64 cols

    // staging: thread t -> LDS row wave*16+(lane>>2), slot lane&3; source slot ^ f(row):
    // f(row) = ((row>>1)&3) ^ ((row>>4)&1) = ((lane>>3)&3) ^ (wave&1) here.
    const int sg16 = (((lane & 3) ^ ((lane >> 3) & 3) ^ (wave & 1)) << 4);
    const char* aG = qx + (size_t)(bm * 256 + wave * 16 + (lane >> 2)) * K + sg16;
    const char* bG = qw + (size_t)(bn * 256 + wave * 16 + (lane >> 2)) * K + sg16;

    // fragment reads: row lane&31, s_need = (lane>>5)+2*half; slot' = s_need ^ f(row);
    // f(row) here = ((lane>>1)&3) ^ ((lane>>4)&1)  (tile bases are 32-multiples -> drop out)
    const int l31 = lane & 31;
    const int fx = ((lane >> 1) & 3) ^ ((lane >> 4) & 1);
    const int fks0 = (((lane >> 5) ^ fx) << 4);
    const int fks1 = ((((lane >> 5) | 2) ^ fx) << 4);
    const int aBase = wm2 * 8192 + l31 * 64;                            // + mi*2048 + fks
    const int bBase = (wn4 >> 1) * 8192 + (wn4 & 1) * 4096 + l31 * 64;  // + ni*2048 + fks

    i32x16 acc[4][2] = {};
    i32x4 XA[4], XB[2], YA[4], YB[2], A1[4], B1[2];

#define STAGE8(s) { const int p_ = (s) & 3;                                                  \
    load_lds16(aG + (size_t)(s) * 64,                   ldsA + p_ * 16384 + wave * 1024);    \
    load_lds16(aG + (size_t)128 * K + (size_t)(s) * 64, ldsA + p_ * 16384 + 8192 + wave * 1024); \
    load_lds16(bG + (size_t)(s) * 64,                   ldsB + p_ * 16384 + wave * 1024);    \
    load_lds16(bG + (size_t)128 * K + (size_t)(s) * 64, ldsB + p_ * 16384 + 8192 + wave * 1024); }

#define PHASE(s, CA, CB, NA, NB, VMN, DO_ST, DO_NXT) {                                       \
    asm volatile("s_waitcnt vmcnt(%0)" :: "n"(VMN) : "memory");                              \
    __builtin_amdgcn_s_barrier();                                                            \
    __builtin_amdgcn_sched_barrier(0);                                                       \
    if (DO_ST) STAGE8((s) + 3);                                                              \
    { const char* Ab_ = ldsA + ((s) & 3) * 16384 + aBase;                                    \
      const char* Bb_ = ldsB + ((s) & 3) * 16384 + bBase;                                    \
      _Pragma("unroll") for (int mi = 0; mi < 4; ++mi)                                       \
          A1[mi] = *(const i32x4*)(Ab_ + mi * 2048 + fks1);                                  \
      _Pragma("unroll") for (int ni = 0; ni < 2; ++ni)                                       \
          B1[ni] = *(const i32x4*)(Bb_ + ni * 2048 + fks1);                                  \
    }                                                                                        \
    __builtin_amdgcn_sched_barrier(0);                                                       \
    __builtin_amdgcn_s_setprio(1);                                                           \
    _Pragma("unroll") for (int mi = 0; mi < 4; ++mi)                                         \
    _Pragma("unroll") for (int ni = 0; ni < 2; ++ni)                                         \
        acc[mi][ni] = __builtin_amdgcn_mfma_i32_32x32x32_i8(CA[mi], CB[ni], acc[mi][ni], 0, 0, 0); \
    __builtin_amdgcn_s_setprio(0);                                                           \
    __builtin_amdgcn_sched_barrier(0);                                                       \
    if (DO_NXT) {                                                                            \
      const char* An_ = ldsA + (((s) + 1) & 3) * 16384 + aBase;                              \
      const char* Bn_ = ldsB + (((s) + 1) & 3) * 16384 + bBase;                              \
      _Pragma("unroll") for (int mi = 0; mi < 4; ++mi)                                       \
          NA[mi] = *(const i32x4*)(An_ + mi * 2048 + fks0);                                  \
      _Pragma("unroll") for (int ni = 0; ni < 2; ++ni)                                       \
          NB[ni] = *(const i32x4*)(Bn_ + ni * 2048 + fks0);                                  \
    }                                                                                        \
    __builtin_amdgcn_sched_barrier(0);                                                       \
    __builtin_amdgcn_s_setprio(1);                                                           \
    _Pragma("unroll") for (int mi = 0; mi < 4; ++mi)                                         \
    _Pragma("unroll") for (int ni = 0; ni < 2; ++ni)                                         \
        acc[mi][ni] = __builtin_amdgcn_mfma_i32_32x32x32_i8(A1[mi], B1[ni], acc[mi][ni], 0, 0, 0); \
    __builtin_amdgcn_s_setprio(0); }

    // prologue: 3 slabs in flight; read slab0 first-half into X
    STAGE8(0); STAGE8(1); STAGE8(2);
    asm volatile("s_waitcnt vmcnt(8)" ::: "memory");   // slab 0 landed (own loads)
    __builtin_amdgcn_s_barrier();                      // -> landed for all waves
    __builtin_amdgcn_sched_barrier(0);
    {
        const char* Ab_ = ldsA + aBase;
        const char* Bb_ = ldsB + bBase;
#pragma unroll
        for (int mi = 0; mi < 4; ++mi) XA[mi] = *(const i32x4*)(Ab_ + mi * 2048 + fks0);
#pragma unroll
        for (int ni = 0; ni < 2; ++ni) XB[ni] = *(const i32x4*)(Bb_ + ni * 2048 + fks0);
    }

    for (int s = 0; s < 60; s += 2) {
        PHASE(s,     XA, XB, YA, YB, 4, true, true);
        PHASE(s + 1, YA, YB, XA, XB, 4, true, true);
    }
    PHASE(60, XA, XB, YA, YB, 4, true,  true);
    PHASE(61, YA, YB, XA, XB, 4, false, true);
    PHASE(62, XA, XB, YA, YB, 0, false, true);
    PHASE(63, YA, YB, XA, XB, 0, false, false);

#undef PHASE
#undef STAGE8

    // ---- Phase A: absmax only (C/D: col=lane&31, row=(reg&3)+8*(reg>>2)+4*(lane>>5)) ----
    float sx, sw;
    load_scales(amax, sx, sw);
    const float s = sx * sw;
    const int col = l31;
    const int r4 = (lane >> 5) * 4;
    float am = 0.f;
    float bqv[2];
#pragma unroll
    for (int ni = 0; ni < 2; ++ni) bqv[ni] = bq[bn * 256 + wn4 * 64 + ni * 32 + col];

#pragma unroll
    for (int mi = 0; mi < 4; ++mi)
#pragma unroll
        for (int reg = 0; reg < 16; ++reg)
#pragma unroll
            for (int ni = 0; ni < 2; ++ni) {
                float o = fmaf(s, (float)acc[mi][ni][reg], bqv[ni]);  // exact: |acc| < 2^24
                am = fmaxf(am, fabsf(o));
            }
    am = wave_max64(am);
    float* red = (float*)lds;   // slot-0 bytes; final K-phase reads were slot 3 -> no collision
    if (lane == 0) red[wave] = am;
    __syncthreads();

    // ---- grid rendezvous: device-scope counter + bounded spin (all 256 blocks co-resident) --
    unsigned* amax_out = ws + 132;
    unsigned* done = ws + 136;
    unsigned* flag = ws + 140;
    if (tid == 0) {
        float r = fmaxf(fmaxf(fmaxf(red[0], red[1]), fmaxf(red[2], red[3])),
                        fmaxf(fmaxf(red[4], red[5]), fmaxf(red[6], red[7])));
        atomicMax(amax_out, __float_as_uint(r));
        __threadfence();
        unsigned old = atomicAdd(done, 1u);
        float so = -1.f;
        if (old == 255u) {
            __threadfence();
            atomicOr(flag, 1u);
            so = fmaxf(__uint_as_float(atomicMax(amax_out, 0u)) / 127.0f, EPSQ);
        } else {
            int iters = 0;
            while (__hip_atomic_load(done, __ATOMIC_RELAXED, __HIP_MEMORY_SCOPE_AGENT) < 256u) {
                __builtin_amdgcn_s_sleep(2);
                if (++iters > 150000) break;
            }
            if (iters > 150000) {
                atomicOr(flag, 2u);          // poison: final_quant will finish the job
            } else {
                __threadfence();
                so = fmaxf(__uint_as_float(atomicMax(amax_out, 0u)) / 127.0f, EPSQ);
            }
        }
        red[12] = so;
    }
    __syncthreads();
    const float so = red[12];

    // ---- Phase B: recompute o from live acc; store final (quantized) value once ----
#pragma unroll
    for (int mi = 0; mi < 4; ++mi) {
#pragma unroll
        for (int reg = 0; reg < 16; ++reg) {
            const int row = (reg & 3) + 8 * (reg >> 2) + r4;
            const int m = bm * 256 + wm2 * 128 + mi * 32 + row;
            float* orow = out + (size_t)m * N + bn * 256 + wn4 * 64 + col;
#pragma unroll
            for (int ni = 0; ni < 2; ++ni) {
                float o = fmaf(s, (float)acc[mi][ni][reg], bqv[ni]);
                if (so > 0.f)
                    o = fminf(fmaxf(rintf(o / so), -127.f), 127.f) * so;
                orow[ni * 32] = o;
            }
        }
    }
}

// ---------------- kernel 4: final fake-quant — early-exits when gemm finalized ----------------
__global__ __launch_bounds__(256) void final_quant(
    float4* __restrict__ out, const unsigned* __restrict__ ws)
{
    if (ws[140] == 1u) return;    // gemm's spin path completed everywhere (idempotent otherwise)
    const float so = fmaxf(__uint_as_float(ws[132]) / 127.0f, EPSQ);
    int i = blockIdx.x * 256 + threadIdx.x;
#pragma unroll
    for (int it = 0; it < 8; ++it, i += STRIDE_MEM) {
        float4 v = out[i];
        v.x = fminf(fmaxf(rintf(v.x / so), -127.f), 127.f) * so;
        v.y = fminf(fmaxf(rintf(v.y / so), -127.f), 127.f) * so;
        v.z = fminf(fmaxf(rintf(v.z / so), -127.f), 127.f) * so;
        v.w = fminf(fmaxf(rintf(v.w / so), -127.f), 127.f) * so;
        out[i] = v;
    }
}

extern "C" void kernel_launch(void* const* d_in, const int* in_sizes, int n_in,
                              void* d_out, int out_size, void* d_ws, size_t ws_size,
                              hipStream_t stream) {
    const float* x = (const float*)d_in[0];   // [4096,4096]
    const float* w = (const float*)d_in[1];   // [4096,4096] (out,in)
    const float* b = (const float*)d_in[2];   // [4096]
    float* out = (float*)d_out;               // [4096,4096] fp32

    char* ws = (char*)d_ws;
    unsigned* amax = (unsigned*)ws;                         // u32 slot layout (<= 1 KB)
    float* bq = (float*)(ws + 1024);                        // 16 KB
    char* qx = (char*)(ws + 32768);                         // 16 MB int8
    char* qw = (char*)(ws + 32768 + (size_t)NELEM);         // 16 MB int8

    hipMemsetAsync(amax, 0, 1024, stream);   // zeroes amax slots + done + flag each launch
    hipLaunchKernelGGL(absmax_xwb, dim3(2048), dim3(256), 0, stream,
                       (const float4*)x, (const float4*)w, b, amax);
    hipLaunchKernelGGL(quant_xwb, dim3(2048), dim3(256), 0, stream,
                       (const float4*)x, (const float4*)w, b, amax,
                       (int*)qx, (int*)qw, bq);
    hipLaunchKernelGGL(gemm_i8_8p, dim3(256), dim3(512), 0, stream,
                       (const char*)qx, (const char*)qw, bq, amax, out, amax);
    hipLaunchKernelGGL(final_quant, dim3(2048), dim3(256), 0, stream,
                       (float4*)out, amax);
}